// Round 6
// baseline (294.120 us; speedup 1.0000x reference)
//
#include <hip/hip_runtime.h>
#include <hip/hip_bf16.h>

// MaskedAttentionLayer: B=4, N=4096, D=256, fp32 in/out.
// mask keeps strictly-future (m>n); softmax over QUERY axis (per-column).
// O = E @ (V/colsum), E = exp(S/16); col m=0 fully masked -> V[b,0,:]/4096.
//
// r15: E never materialized (k_scoresA colsum -> k_vpt -> k_fused).
// r16 profile: k_fused 115.5us, Occupancy 6% (1 block/CU, exposed latency),
// LDS bank conflicts 532K (QK A-read: 32 rows x 512B stride, 8-way).
// r17: k_fused v2 —
//   (1) K tile staged GRANULE-MAJOR ([g][row], row stride 16B) via per-lane
//       global source remap; QK A-read = 32 consecutive lanes -> consecutive
//       16B slots: conflict-free by construction, no XOR.
//   (2) ksh double-buffered (2x32KB): next K DMA issued at step top, lands
//       across the whole step (was: single buffer, PV-window only).
//   (3) d-half split: block = (b, NT, dh) -> 512 blocks = 2 blocks/CU
//       (LDS 72KB), 8 waves/CU. QK duplicated per half (cheap) but accO/bb
//       halve and cross-block overlap hides step latency.

typedef float f32x4 __attribute__((ext_vector_type(4)));
typedef float f32x16 __attribute__((ext_vector_type(16)));
typedef __bf16 bf16x8 __attribute__((ext_vector_type(8)));
typedef __bf16 bf16x4 __attribute__((ext_vector_type(4)));

#define MFMA16(a, b, c) __builtin_amdgcn_mfma_f32_16x16x32_bf16((a), (b), (c), 0, 0, 0)
#define MFMA32(a, b, c) __builtin_amdgcn_mfma_f32_32x32x16_bf16((a), (b), (c), 0, 0, 0)

constexpr int SEQ = 4096;
constexpr int DIM = 256;

// async global->LDS DMA, 16B/lane (dest = wave-uniform base + lane*16)
__device__ __forceinline__ void gl16(const __bf16* g, __bf16* l) {
  __builtin_amdgcn_global_load_lds((const __attribute__((address_space(1))) void*)g,
                                   (__attribute__((address_space(3))) void*)l, 16, 0, 0);
}

// ---------------------------------------------------------------- k_prep
__global__ void k_prep(const float* __restrict__ Wq, const float* __restrict__ Wk,
                       const float* __restrict__ Wv, __bf16* __restrict__ Wb,
                       float* __restrict__ colsum) {
  int i = blockIdx.x * 256 + threadIdx.x;
  if (i < 3 * 65536) {
    const float* src = (i < 65536) ? Wq : (i < 131072 ? Wk : Wv);
    Wb[i] = (__bf16)src[i & 65535];
  }
  if (i < 4 * SEQ) colsum[i] = 0.f;
}

// ---------------------------------------------------------------- k_qkv
// (r6-verified, unchanged)
__global__ __launch_bounds__(256, 2) void k_qkv(const float* __restrict__ x,
                                                const __bf16* __restrict__ Wb,
                                                __bf16* __restrict__ Qb,
                                                __bf16* __restrict__ Kb,
                                                __bf16* __restrict__ Vb) {
  __shared__ __bf16 wsh[64][264];
  const int t = threadIdx.x, lane = t & 63, w = t >> 6;
  const int ln = lane & 15, quad = lane >> 4, q8 = quad * 8;
  const int i0 = blockIdx.x * 64;
  bf16x8 xa[8];
#pragma unroll
  for (int kf = 0; kf < 8; ++kf) {
    const float* src = &x[(size_t)(i0 + w * 16 + ln) * DIM + kf * 32 + q8];
    float4 v0 = *(const float4*)&src[0];
    float4 v1 = *(const float4*)&src[4];
    xa[kf] = bf16x8{(__bf16)v0.x, (__bf16)v0.y, (__bf16)v0.z, (__bf16)v0.w,
                    (__bf16)v1.x, (__bf16)v1.y, (__bf16)v1.z, (__bf16)v1.w};
  }
  for (int zj = 0; zj < 12; ++zj) {
    const int z = zj >> 2, j0 = (zj & 3) * 64;
    const __bf16* W = Wb + z * 65536 + j0 * 256;
    bf16x8 stg[8];
#pragma unroll
    for (int i = 0; i < 8; ++i) stg[i] = *(const bf16x8*)&W[(t + i * 256) * 8];
    __syncthreads();
#pragma unroll
    for (int i = 0; i < 8; ++i)
      *(bf16x8*)&wsh[(t >> 5) + i * 8][(t & 31) * 8] = stg[i];
    __syncthreads();
    f32x4 acc[4] = {};
#pragma unroll
    for (int kf = 0; kf < 8; ++kf) {
      bf16x8 bb[4];
#pragma unroll
      for (int tj = 0; tj < 4; ++tj)
        bb[tj] = *(bf16x8*)&wsh[tj * 16 + ln][kf * 32 + q8];
#pragma unroll
      for (int tj = 0; tj < 4; ++tj) acc[tj] = MFMA16(xa[kf], bb[tj], acc[tj]);
    }
    __bf16* Out = (z == 0) ? Qb : (z == 1 ? Kb : Vb);
#pragma unroll
    for (int tj = 0; tj < 4; ++tj)
#pragma unroll
      for (int r = 0; r < 4; ++r) {
        int row = i0 + w * 16 + quad * 4 + r;
        int col = j0 + tj * 16 + ln;
        Out[(size_t)row * DIM + col] = (__bf16)acc[tj][r];
      }
  }
}

// ---------------------------------------------------------------- k_scoresA
// k_scores (r10-verified) minus the E store: colsum only, all m-tiles in
// one dispatch.
__global__ __launch_bounds__(256, 2) void k_scoresA(const __bf16* __restrict__ Qb,
                                                    const __bf16* __restrict__ Kb,
                                                    float* __restrict__ colsum) {
  __shared__ __bf16 qsh[2 * 64 * 256];  // 64 KB dbuf
  const int t = threadIdx.x, lane = t & 63, w = t >> 6;
  const int ln = lane & 15, quad = lane >> 4, q8 = quad * 8;
  const int bid = blockIdx.x;
  const int b = (bid & 7) >> 1;                    // XCD-pair pinned batch
  const int rest = ((bid >> 3) << 1) | (bid & 1);  // 0..255
  const int mt = rest >> 2;
  const int s = rest & 3;
  if (s > mt) return;
  const int m0 = mt * 64;
  const __bf16* Qp = Qb + (size_t)b * SEQ * DIM;
  const __bf16* Kp = Kb + (size_t)b * SEQ * DIM;
  bf16x8 kb[8];
#pragma unroll
  for (int kf = 0; kf < 8; ++kf)
    kb[kf] = *(const bf16x8*)&Kp[(size_t)(m0 + w * 16 + ln) * DIM + kf * 32 + q8];
  auto stageq = [&](int ncv, int buf) {
    const __bf16* src = Qp + (size_t)ncv * 16384;
#pragma unroll
    for (int i2 = 0; i2 < 8; ++i2) {
      int sl = t + i2 * 256;
      int row = sl >> 5, g = sl & 31;
      gl16(&src[row * 256 + ((g ^ (row & 15)) << 3)], &qsh[buf * 16384 + sl * 8]);
    }
  };
  float csum4[4] = {0.f, 0.f, 0.f, 0.f};
  int nc = s, cur = 0;
  if (nc <= mt) stageq(nc, 0);
  for (; nc <= mt; nc += 4, cur ^= 1) {
    __syncthreads();  // Q[cur] staged (full-step overlap)
    if (nc + 4 <= mt) stageq(nc + 4, cur ^ 1);
    f32x4 accST[4] = {};
#pragma unroll
    for (int kf = 0; kf < 8; ++kf) {
#pragma unroll
      for (int tn = 0; tn < 4; ++tn) {
        int row = tn * 16 + ln;
        bf16x8 bq = *(const bf16x8*)&qsh[cur * 16384 + row * 256 +
                                         (((kf * 4 + quad) ^ ln) << 3)];
        accST[tn] = MFMA16(kb[kf], bq, accST[tn]);
      }
    }
#pragma unroll
    for (int tn = 0; tn < 4; ++tn) {
      int n_g = nc * 64 + tn * 16 + ln;
      int mb = m0 + w * 16 + quad * 4;
#pragma unroll
      for (int r = 0; r < 4; ++r) {
        float e = (n_g < mb + r) ? __expf(accST[tn][r] * 0.0625f) : 0.f;
        csum4[r] += e;
      }
    }
  }
#pragma unroll
  for (int r = 0; r < 4; ++r) {
    float v = csum4[r];
    v += __shfl_xor(v, 1);
    v += __shfl_xor(v, 2);
    v += __shfl_xor(v, 4);
    v += __shfl_xor(v, 8);
    if (ln == 0) atomicAdd(&colsum[b * SEQ + m0 + w * 16 + quad * 4 + r], v);
  }
}

// ---------------------------------------------------------------- k_vpt
// (r10-verified, unchanged) swizzled VpTblk[b][mblk][d][m'] = V/colsum.
__global__ void k_vpt(const __bf16* __restrict__ Vb, const float* __restrict__ colsum,
                      __bf16* __restrict__ VpT, int mtLo) {
  __shared__ __bf16 tile[64][72];
  const int t = threadIdx.x;
  const int b = blockIdx.z;
  const int mblk = mtLo + blockIdx.x;
  const int m0 = mblk * 64, d0 = blockIdx.y * 64;
  {
    int row = t >> 2, part = t & 3;
    float cs = colsum[b * SEQ + m0 + row];
    float inv = (m0 + row == 0) ? (1.0f / 4096.0f) : (1.0f / cs);
#pragma unroll
    for (int i = 0; i < 2; ++i) {
      int c = part * 2 + i;
      bf16x8 v = *(const bf16x8*)&Vb[(size_t)(b * SEQ + m0 + row) * DIM + d0 + c * 8];
      bf16x8 o;
#pragma unroll
      for (int j = 0; j < 8; ++j) o[j] = (__bf16)((float)v[j] * inv);
      *(bf16x8*)&tile[row][c * 8] = o;
    }
  }
  __syncthreads();
  {
    int row = t >> 2, part = t & 3;  // row = d-local
#pragma unroll
    for (int i = 0; i < 2; ++i) {
      int c = part * 2 + i;  // logical m-part
      bf16x8 o;
#pragma unroll
      for (int j = 0; j < 8; ++j) o[j] = tile[c * 8 + j][row];
      *(bf16x8*)&VpT[(size_t)((b * 64 + mblk) * 256 + d0 + row) * 64 +
                     ((c ^ (row & 7)) << 3)] = o;
    }
  }
}

// ---------------------------------------------------------------- k_fused v2
// block = (b, 64-row n-tile NT, d-half dh). O[n-tile][dh*128..+128) =
// sum_{ms>=NT} exp(mask(Q K^T)) . Vp, + V0/4096 on every row.
// K tile staged granule-major ksh[g][row] (row stride 16B) -> QK A-read is
// lane-consecutive 16B, conflict-free. ksh double-buffered; next-K DMA
// issued at step top. QK at 32x32x16 (2x2 wave quadrants), P -> psh
// (E-layout, verified), PV at 16x16x32 (verified pa/bb), direct fp32 out.
__global__ __launch_bounds__(256, 2) void k_fused(const __bf16* __restrict__ Qb,
                                                  const __bf16* __restrict__ Kb,
                                                  const __bf16* __restrict__ VpT,
                                                  const __bf16* __restrict__ Vb,
                                                  float* __restrict__ out) {
  __shared__ __bf16 ksh[2][64 * 256];  // 2 x 32 KB K tile, granule-major
  __shared__ __bf16 psh[64 * 64];      // 8 KB P tile (E-layout)
  const int t = threadIdx.x, lane = t & 63, w = t >> 6;
  const int ln = lane & 15, quad = lane >> 4;
  const int l32 = lane & 31, hi = lane >> 5;
  const int bid = blockIdx.x;
  const int b = (bid & 7) >> 1;                    // XCD-pair pinned batch
  const int rest = ((bid >> 3) << 1) | (bid & 1);  // 0..127
  const int dh = rest & 1;
  const int pp = rest >> 1;  // 0..63
  const int NT = (pp & 1) ? (63 - (pp >> 1)) : (pp >> 1);  // long/short mix
  const int n0 = NT * 64;
  const __bf16* Qp = Qb + (size_t)b * SEQ * DIM;
  const __bf16* Kp = Kb + (size_t)b * SEQ * DIM;
  const __bf16* Vt = VpT + (size_t)b * SEQ * DIM;
  const int tm = w >> 1, tn32 = w & 1;  // QK quadrant of this wave
  // resident Q B-frags (32x32x16): col n = n0+tn32*32+l32, k = kf*16+hi*8
  bf16x8 qb[16];
#pragma unroll
  for (int kf = 0; kf < 16; ++kf)
    qb[kf] = *(const bf16x8*)&Qp[(size_t)(n0 + tn32 * 32 + l32) * DIM + kf * 16 + hi * 8];
  // stage K[ms] granule-major: LDS 16B-slot sl = g*64+row <- K[row][g*8..]
  auto stagek = [&](int ms, int buf) {
    const __bf16* src = Kp + (size_t)ms * 16384;
#pragma unroll
    for (int i2 = 0; i2 < 8; ++i2) {
      int sl = t + i2 * 256;
      int row = sl & 63, g = sl >> 6;
      gl16(&src[row * 256 + g * 8], &ksh[buf][sl * 8]);
    }
  };
  f32x4 accO[4][2] = {};  // [t16][td]; wave w owns d in [dh*128+w*32, +32)
  stagek(NT, 0);
  int cur = 0;
  for (int ms = NT; ms < 64; ++ms, cur ^= 1) {
    __syncthreads();  // B1: K[cur] DMA complete; prev-step psh reads done
    if (ms + 1 < 64) stagek(ms + 1, cur ^ 1);  // lands across whole step
    // ---- QK^T: A = K rows (tm*32+l32) from granule-major LDS, B = qb
    f32x16 accS = {};
#pragma unroll
    for (int kf = 0; kf < 16; ++kf) {
      bf16x8 ka = *(const bf16x8*)&ksh[cur][((kf * 2 + hi) * 64 + tm * 32 + l32) * 8];
      accS = MFMA32(ka, qb[kf], accS);
    }
    // ---- mask + exp + pack -> psh (E-layout [n][m-part ^ (n&7)])
    {
      int nrow = tn32 * 32 + l32;
      int n_gl = n0 + nrow;
#pragma unroll
      for (int rr = 0; rr < 4; ++rr) {
        int mbase = ms * 64 + tm * 32 + rr * 8 + hi * 4;
        bf16x4 pk;
#pragma unroll
        for (int r = 0; r < 4; ++r) {
          float e = (n_gl < mbase + r) ? __expf(accS[rr * 4 + r] * 0.0625f) : 0.f;
          pk[r] = (__bf16)e;
        }
        int p8 = tm * 4 + rr;
        *(bf16x4*)&psh[nrow * 64 + ((p8 ^ (nrow & 7)) << 3) + hi * 4] = pk;
      }
    }
    __syncthreads();  // B2: psh complete
    // ---- PV (16x16x32): A = P (psh), B = VpT direct (L2-resident)
    const __bf16* vp = Vt + (size_t)ms * 16384;
    bf16x8 bb[2][2];
#pragma unroll
    for (int kf = 0; kf < 2; ++kf)
#pragma unroll
      for (int td = 0; td < 2; ++td) {
        int d = dh * 128 + w * 32 + td * 16 + ln;
        bb[kf][td] = *(const bf16x8*)&vp[d * 64 + (((kf * 4 + quad) ^ (d & 7)) << 3)];
      }
#pragma unroll
    for (int t16 = 0; t16 < 4; ++t16) {
      int row = t16 * 16 + ln;
      bf16x8 pa[2];
#pragma unroll
      for (int kf = 0; kf < 2; ++kf)
        pa[kf] = *(const bf16x8*)&psh[row * 64 + (((kf * 4 + quad) ^ (row & 7)) << 3)];
#pragma unroll
      for (int td = 0; td < 2; ++td)
#pragma unroll
        for (int kf = 0; kf < 2; ++kf)
          accO[t16][td] = MFMA16(pa[kf], bb[kf][td], accO[t16][td]);
    }
  }
  // epilogue: direct fp32 store; every row gets the V0/4096 (masked col 0) term
  float* Op = out + ((size_t)b << 20);
  const __bf16* V0 = Vb + ((size_t)b << 20);
#pragma unroll
  for (int t16 = 0; t16 < 4; ++t16)
#pragma unroll
    for (int td = 0; td < 2; ++td) {
      int col = dh * 128 + w * 32 + td * 16 + ln;
      float c0 = (float)V0[col] * (1.0f / 4096.0f);
#pragma unroll
      for (int r = 0; r < 4; ++r) {
        int row = n0 + t16 * 16 + quad * 4 + r;
        Op[(size_t)row * DIM + col] = accO[t16][td][r] + c0;
      }
    }
}

// ---------------------------------------------------------------- launch
extern "C" void kernel_launch(void* const* d_in, const int* in_sizes, int n_in,
                              void* d_out, int out_size, void* d_ws, size_t ws_size,
                              hipStream_t stream) {
  const float* x = (const float*)d_in[0];
  const float* Wq = (const float*)d_in[1];
  const float* Wk = (const float*)d_in[2];
  const float* Wv = (const float*)d_in[3];
  float* out = (float*)d_out;
  char* ws = (char*)d_ws;
  __bf16* Qb = (__bf16*)(ws);                             // 8 MB
  __bf16* Kb = (__bf16*)(ws + (8u << 20));                // 8 MB
  __bf16* Vb = (__bf16*)(ws + (16u << 20));               // 8 MB
  __bf16* VpT = (__bf16*)(ws + (24u << 20));              // 8 MB (blocked+swizzled)
  float* colsum = (float*)(ws + (32u << 20));             // 64 KB
  __bf16* Wb = (__bf16*)(ws + (32u << 20) + (1u << 16));  // 384 KB

  k_prep<<<dim3(768), dim3(256), 0, stream>>>(Wq, Wk, Wv, Wb, colsum);
  k_qkv<<<dim3(256), dim3(256), 0, stream>>>(x, Wb, Qb, Kb, Vb);
  k_scoresA<<<dim3(16 * 64), dim3(256), 0, stream>>>(Qb, Kb, colsum);
  k_vpt<<<dim3(64, 4, 4), dim3(256), 0, stream>>>(Vb, colsum, VpT, 0);
  k_fused<<<dim3(512), dim3(256), 0, stream>>>(Qb, Kb, VpT, Vb, out);
}

// Round 7
// 220.850 us; speedup vs baseline: 1.3318x; 1.3318x over previous
//
#include <hip/hip_runtime.h>
#include <hip/hip_bf16.h>

// MaskedAttentionLayer: B=4, N=4096, D=256, fp32 in/out.
// mask keeps strictly-future (m>n); softmax over QUERY axis (per-column).
// O = E @ (V/colsum), E = exp(S/16); col m=0 fully masked -> V[b,0,:]/4096.
//
// r15/r16: E never materialized; k_fused = streaming QK^T->exp->PV.
// r16 profile: k_fused 115.5us, occupancy 6% (256 blocks = 1/CU, chains to
// 64 steps, ~4300cy/step of EXPOSED latency; 69 GFLOP is ~0.1us of MFMA).
// r17 (granule-major + dh split) regressed: uncoalesced staging, dup QK;
// conflicts proved to be psh-path and ~1% of runtime (red herring).
// r18: TLP + shorter chains. Chunk each (b,NT) chain into <=16-step chunk
// blocks (grid 1024, 640 active ~2.5-4/CU; LDS 40KB, VGPR ~124 both allow
// 4/CU). Chunks write bf16 partial O-tiles (32KB) to a compact 20MB ws
// scratch with PLAIN stores (no atomics — r14 lesson); k_red sums <=4
// partials + V0/4096 -> fp32 out. Per-step machinery = r16 verbatim.

typedef float f32x4 __attribute__((ext_vector_type(4)));
typedef float f32x16 __attribute__((ext_vector_type(16)));
typedef __bf16 bf16x8 __attribute__((ext_vector_type(8)));
typedef __bf16 bf16x4 __attribute__((ext_vector_type(4)));

#define MFMA16(a, b, c) __builtin_amdgcn_mfma_f32_16x16x32_bf16((a), (b), (c), 0, 0, 0)
#define MFMA32(a, b, c) __builtin_amdgcn_mfma_f32_32x32x16_bf16((a), (b), (c), 0, 0, 0)

constexpr int SEQ = 4096;
constexpr int DIM = 256;

// async global->LDS DMA, 16B/lane (dest = wave-uniform base + lane*16)
__device__ __forceinline__ void gl16(const __bf16* g, __bf16* l) {
  __builtin_amdgcn_global_load_lds((const __attribute__((address_space(1))) void*)g,
                                   (__attribute__((address_space(3))) void*)l, 16, 0, 0);
}

// ---------------------------------------------------------------- k_prep
__global__ void k_prep(const float* __restrict__ Wq, const float* __restrict__ Wk,
                       const float* __restrict__ Wv, __bf16* __restrict__ Wb,
                       float* __restrict__ colsum) {
  int i = blockIdx.x * 256 + threadIdx.x;
  if (i < 3 * 65536) {
    const float* src = (i < 65536) ? Wq : (i < 131072 ? Wk : Wv);
    Wb[i] = (__bf16)src[i & 65535];
  }
  if (i < 4 * SEQ) colsum[i] = 0.f;
}

// ---------------------------------------------------------------- k_qkv
// (r6-verified, unchanged)
__global__ __launch_bounds__(256, 2) void k_qkv(const float* __restrict__ x,
                                                const __bf16* __restrict__ Wb,
                                                __bf16* __restrict__ Qb,
                                                __bf16* __restrict__ Kb,
                                                __bf16* __restrict__ Vb) {
  __shared__ __bf16 wsh[64][264];
  const int t = threadIdx.x, lane = t & 63, w = t >> 6;
  const int ln = lane & 15, quad = lane >> 4, q8 = quad * 8;
  const int i0 = blockIdx.x * 64;
  bf16x8 xa[8];
#pragma unroll
  for (int kf = 0; kf < 8; ++kf) {
    const float* src = &x[(size_t)(i0 + w * 16 + ln) * DIM + kf * 32 + q8];
    float4 v0 = *(const float4*)&src[0];
    float4 v1 = *(const float4*)&src[4];
    xa[kf] = bf16x8{(__bf16)v0.x, (__bf16)v0.y, (__bf16)v0.z, (__bf16)v0.w,
                    (__bf16)v1.x, (__bf16)v1.y, (__bf16)v1.z, (__bf16)v1.w};
  }
  for (int zj = 0; zj < 12; ++zj) {
    const int z = zj >> 2, j0 = (zj & 3) * 64;
    const __bf16* W = Wb + z * 65536 + j0 * 256;
    bf16x8 stg[8];
#pragma unroll
    for (int i = 0; i < 8; ++i) stg[i] = *(const bf16x8*)&W[(t + i * 256) * 8];
    __syncthreads();
#pragma unroll
    for (int i = 0; i < 8; ++i)
      *(bf16x8*)&wsh[(t >> 5) + i * 8][(t & 31) * 8] = stg[i];
    __syncthreads();
    f32x4 acc[4] = {};
#pragma unroll
    for (int kf = 0; kf < 8; ++kf) {
      bf16x8 bb[4];
#pragma unroll
      for (int tj = 0; tj < 4; ++tj)
        bb[tj] = *(bf16x8*)&wsh[tj * 16 + ln][kf * 32 + q8];
#pragma unroll
      for (int tj = 0; tj < 4; ++tj) acc[tj] = MFMA16(xa[kf], bb[tj], acc[tj]);
    }
    __bf16* Out = (z == 0) ? Qb : (z == 1 ? Kb : Vb);
#pragma unroll
    for (int tj = 0; tj < 4; ++tj)
#pragma unroll
      for (int r = 0; r < 4; ++r) {
        int row = i0 + w * 16 + quad * 4 + r;
        int col = j0 + tj * 16 + ln;
        Out[(size_t)row * DIM + col] = (__bf16)acc[tj][r];
      }
  }
}

// ---------------------------------------------------------------- k_scoresA
// k_scores (r10-verified) minus the E store: colsum only, all m-tiles in
// one dispatch.
__global__ __launch_bounds__(256, 2) void k_scoresA(const __bf16* __restrict__ Qb,
                                                    const __bf16* __restrict__ Kb,
                                                    float* __restrict__ colsum) {
  __shared__ __bf16 qsh[2 * 64 * 256];  // 64 KB dbuf
  const int t = threadIdx.x, lane = t & 63, w = t >> 6;
  const int ln = lane & 15, quad = lane >> 4, q8 = quad * 8;
  const int bid = blockIdx.x;
  const int b = (bid & 7) >> 1;                    // XCD-pair pinned batch
  const int rest = ((bid >> 3) << 1) | (bid & 1);  // 0..255
  const int mt = rest >> 2;
  const int s = rest & 3;
  if (s > mt) return;
  const int m0 = mt * 64;
  const __bf16* Qp = Qb + (size_t)b * SEQ * DIM;
  const __bf16* Kp = Kb + (size_t)b * SEQ * DIM;
  bf16x8 kb[8];
#pragma unroll
  for (int kf = 0; kf < 8; ++kf)
    kb[kf] = *(const bf16x8*)&Kp[(size_t)(m0 + w * 16 + ln) * DIM + kf * 32 + q8];
  auto stageq = [&](int ncv, int buf) {
    const __bf16* src = Qp + (size_t)ncv * 16384;
#pragma unroll
    for (int i2 = 0; i2 < 8; ++i2) {
      int sl = t + i2 * 256;
      int row = sl >> 5, g = sl & 31;
      gl16(&src[row * 256 + ((g ^ (row & 15)) << 3)], &qsh[buf * 16384 + sl * 8]);
    }
  };
  float csum4[4] = {0.f, 0.f, 0.f, 0.f};
  int nc = s, cur = 0;
  if (nc <= mt) stageq(nc, 0);
  for (; nc <= mt; nc += 4, cur ^= 1) {
    __syncthreads();  // Q[cur] staged (full-step overlap)
    if (nc + 4 <= mt) stageq(nc + 4, cur ^ 1);
    f32x4 accST[4] = {};
#pragma unroll
    for (int kf = 0; kf < 8; ++kf) {
#pragma unroll
      for (int tn = 0; tn < 4; ++tn) {
        int row = tn * 16 + ln;
        bf16x8 bq = *(const bf16x8*)&qsh[cur * 16384 + row * 256 +
                                         (((kf * 4 + quad) ^ ln) << 3)];
        accST[tn] = MFMA16(kb[kf], bq, accST[tn]);
      }
    }
#pragma unroll
    for (int tn = 0; tn < 4; ++tn) {
      int n_g = nc * 64 + tn * 16 + ln;
      int mb = m0 + w * 16 + quad * 4;
#pragma unroll
      for (int r = 0; r < 4; ++r) {
        float e = (n_g < mb + r) ? __expf(accST[tn][r] * 0.0625f) : 0.f;
        csum4[r] += e;
      }
    }
  }
#pragma unroll
  for (int r = 0; r < 4; ++r) {
    float v = csum4[r];
    v += __shfl_xor(v, 1);
    v += __shfl_xor(v, 2);
    v += __shfl_xor(v, 4);
    v += __shfl_xor(v, 8);
    if (ln == 0) atomicAdd(&colsum[b * SEQ + m0 + w * 16 + quad * 4 + r], v);
  }
}

// ---------------------------------------------------------------- k_vpt
// (r10-verified, unchanged) swizzled VpTblk[b][mblk][d][m'] = V/colsum.
__global__ void k_vpt(const __bf16* __restrict__ Vb, const float* __restrict__ colsum,
                      __bf16* __restrict__ VpT, int mtLo) {
  __shared__ __bf16 tile[64][72];
  const int t = threadIdx.x;
  const int b = blockIdx.z;
  const int mblk = mtLo + blockIdx.x;
  const int m0 = mblk * 64, d0 = blockIdx.y * 64;
  {
    int row = t >> 2, part = t & 3;
    float cs = colsum[b * SEQ + m0 + row];
    float inv = (m0 + row == 0) ? (1.0f / 4096.0f) : (1.0f / cs);
#pragma unroll
    for (int i = 0; i < 2; ++i) {
      int c = part * 2 + i;
      bf16x8 v = *(const bf16x8*)&Vb[(size_t)(b * SEQ + m0 + row) * DIM + d0 + c * 8];
      bf16x8 o;
#pragma unroll
      for (int j = 0; j < 8; ++j) o[j] = (__bf16)((float)v[j] * inv);
      *(bf16x8*)&tile[row][c * 8] = o;
    }
  }
  __syncthreads();
  {
    int row = t >> 2, part = t & 3;  // row = d-local
#pragma unroll
    for (int i = 0; i < 2; ++i) {
      int c = part * 2 + i;  // logical m-part
      bf16x8 o;
#pragma unroll
      for (int j = 0; j < 8; ++j) o[j] = tile[c * 8 + j][row];
      *(bf16x8*)&VpT[(size_t)((b * 64 + mblk) * 256 + d0 + row) * 64 +
                     ((c ^ (row & 7)) << 3)] = o;
    }
  }
}

// ---------------------------------------------------------------- k_fused v3
// block = (b, 64-row n-tile NT, chunk c). Chunk covers ms in
// [NT+16c, min(NT+16c+16, 64)). Per-step machinery = r16 verbatim
// (row-major XOR stagek, QK 32x32x16, psh E-layout, PV 16x16x32).
// Output: bf16 partial O-tile [64][256] -> compact scratch slot
// b*160 + prefix(NT) + c. No atomics, no V0 (k_red adds it).
__global__ __launch_bounds__(256, 2) void k_fused(const __bf16* __restrict__ Qb,
                                                  const __bf16* __restrict__ Kb,
                                                  const __bf16* __restrict__ VpT,
                                                  __bf16* __restrict__ partial) {
  __shared__ __bf16 ksh[64 * 256];  // 32 KB K m-tile (swizzled rows)
  __shared__ __bf16 psh[64 * 64];   //  8 KB P tile (E-layout)
  const int t = threadIdx.x, lane = t & 63, w = t >> 6;
  const int ln = lane & 15, quad = lane >> 4;
  const int l32 = lane & 31, hi = lane >> 5;
  const int bid = blockIdx.x;
  const int b = (bid & 7) >> 1;                    // XCD-pair pinned batch
  const int rest = ((bid >> 3) << 1) | (bid & 1);  // 0..255
  const int c = rest & 3;
  const int pp = rest >> 2;  // 0..63
  const int NT = (pp & 1) ? (63 - (pp >> 1)) : (pp >> 1);  // long/short mix
  const int mStart = NT + 16 * c;
  if (mStart >= 64) return;  // inactive chunk
  const int mEnd = (mStart + 16 < 64) ? (mStart + 16) : 64;
  int sb = 0;  // prefix of chunk counts for nt < NT (nch(nt) = ceil((64-nt)/16))
  for (int nt = 0; nt < NT; ++nt) sb += (79 - nt) >> 4;
  const int slot = b * 160 + sb + c;
  const int n0 = NT * 64;
  const __bf16* Qp = Qb + (size_t)b * SEQ * DIM;
  const __bf16* Kp = Kb + (size_t)b * SEQ * DIM;
  const __bf16* Vt = VpT + (size_t)b * SEQ * DIM;
  const int tm = w >> 1, tn32 = w & 1;  // QK quadrant of this wave
  // resident Q B-frags (32x32x16): col n = n0+tn32*32+l32, k = kf*16+hi*8
  bf16x8 qb[16];
#pragma unroll
  for (int kf = 0; kf < 16; ++kf)
    qb[kf] = *(const bf16x8*)&Qp[(size_t)(n0 + tn32 * 32 + l32) * DIM + kf * 16 + hi * 8];
  auto stagek = [&](int ms) {
    const __bf16* src = Kp + (size_t)ms * 16384;
#pragma unroll
    for (int i2 = 0; i2 < 8; ++i2) {
      int sl = t + i2 * 256;
      int row = sl >> 5, g = sl & 31;
      gl16(&src[row * 256 + ((g ^ (row & 15)) << 3)], &ksh[sl * 8]);
    }
  };
  f32x4 accO[4][4] = {};  // [t16][td]; wave w owns d in [w*64, w*64+64)
  stagek(mStart);
  for (int ms = mStart; ms < mEnd; ++ms) {
    __syncthreads();  // B1: K[ms] DMA complete; prev-step psh reads done
    // ---- QK^T: A = K rows (tm*32+l32), B = qb
    f32x16 accS = {};
#pragma unroll
    for (int kf = 0; kf < 16; ++kf) {
      int mrow = tm * 32 + l32;
      bf16x8 ka = *(const bf16x8*)&ksh[mrow * 256 +
                                       (((kf * 2 + hi) ^ (mrow & 15)) << 3)];
      accS = MFMA32(ka, qb[kf], accS);
    }
    // ---- mask + exp + pack -> psh (E-layout [n][m-part ^ (n&7)])
    {
      int nrow = tn32 * 32 + l32;
      int n_gl = n0 + nrow;
#pragma unroll
      for (int rr = 0; rr < 4; ++rr) {
        int mbase = ms * 64 + tm * 32 + rr * 8 + hi * 4;
        bf16x4 pk;
#pragma unroll
        for (int r = 0; r < 4; ++r) {
          float e = (n_gl < mbase + r) ? __expf(accS[rr * 4 + r] * 0.0625f) : 0.f;
          pk[r] = (__bf16)e;
        }
        int p8 = tm * 4 + rr;
        *(bf16x4*)&psh[nrow * 64 + ((p8 ^ (nrow & 7)) << 3) + hi * 4] = pk;
      }
    }
    __syncthreads();  // B2: psh complete; all K reads done
    if (ms + 1 < mEnd) stagek(ms + 1);  // DMA overlaps PV; drained by next B1
    // ---- PV (16x16x32): A = P (psh), B = VpT direct (L2-resident)
    const __bf16* vp = Vt + (size_t)ms * 16384;
    bf16x8 bb[2][4];
#pragma unroll
    for (int kf = 0; kf < 2; ++kf)
#pragma unroll
      for (int td = 0; td < 4; ++td) {
        int d = w * 64 + td * 16 + ln;
        bb[kf][td] = *(const bf16x8*)&vp[d * 64 + (((kf * 4 + quad) ^ (d & 7)) << 3)];
      }
#pragma unroll
    for (int t16 = 0; t16 < 4; ++t16) {
      int row = t16 * 16 + ln;
      bf16x8 pa[2];
#pragma unroll
      for (int kf = 0; kf < 2; ++kf)
        pa[kf] = *(const bf16x8*)&psh[row * 64 + (((kf * 4 + quad) ^ (row & 7)) << 3)];
#pragma unroll
      for (int td = 0; td < 4; ++td)
#pragma unroll
        for (int kf = 0; kf < 2; ++kf)
          accO[t16][td] = MFMA16(pa[kf], bb[kf][td], accO[t16][td]);
    }
  }
  // epilogue: bf16 partial store to compact slot (no V0 term here)
  __bf16* Pp = partial + (size_t)slot * 16384;
#pragma unroll
  for (int t16 = 0; t16 < 4; ++t16)
#pragma unroll
    for (int td = 0; td < 4; ++td) {
      int col = w * 64 + td * 16 + ln;
#pragma unroll
      for (int r = 0; r < 4; ++r) {
        int row = t16 * 16 + quad * 4 + r;
        Pp[row * 256 + col] = (__bf16)accO[t16][td][r];
      }
    }
}

// ---------------------------------------------------------------- k_red
// out[b][NT*64 + n][d] = sum_c partial[slot(b,NT,c)][n][d] + V0[d]/4096.
__global__ void k_red(const __bf16* __restrict__ partial,
                      const __bf16* __restrict__ Vb, float* __restrict__ out) {
  const int NT = blockIdx.x, b = blockIdx.y;
  const int nch = (79 - NT) >> 4;  // ceil((64-NT)/16)
  int sb = 0;
  for (int nt = 0; nt < NT; ++nt) sb += (79 - nt) >> 4;
  const __bf16* base = partial + (size_t)(b * 160 + sb) * 16384;
  const __bf16* V0 = Vb + ((size_t)b << 20);
  float* Op = out + ((size_t)b << 20) + (size_t)NT * 64 * 256;
  const int t = threadIdx.x;
#pragma unroll
  for (int k = 0; k < 8; ++k) {
    int idx8 = t + k * 256;  // 0..2047 ; element offset = idx8*8
    float acc[8] = {0.f, 0.f, 0.f, 0.f, 0.f, 0.f, 0.f, 0.f};
    for (int cc = 0; cc < nch; ++cc) {
      bf16x8 v = *(const bf16x8*)&base[cc * 16384 + idx8 * 8];
#pragma unroll
      for (int j = 0; j < 8; ++j) acc[j] += (float)v[j];
    }
    int d = (idx8 & 31) * 8;
    bf16x8 v0 = *(const bf16x8*)&V0[d];
    float4 o0, o1;
    o0.x = acc[0] + (float)v0[0] * (1.0f / 4096.0f);
    o0.y = acc[1] + (float)v0[1] * (1.0f / 4096.0f);
    o0.z = acc[2] + (float)v0[2] * (1.0f / 4096.0f);
    o0.w = acc[3] + (float)v0[3] * (1.0f / 4096.0f);
    o1.x = acc[4] + (float)v0[4] * (1.0f / 4096.0f);
    o1.y = acc[5] + (float)v0[5] * (1.0f / 4096.0f);
    o1.z = acc[6] + (float)v0[6] * (1.0f / 4096.0f);
    o1.w = acc[7] + (float)v0[7] * (1.0f / 4096.0f);
    *(float4*)&Op[idx8 * 8] = o0;
    *(float4*)&Op[idx8 * 8 + 4] = o1;
  }
}

// ---------------------------------------------------------------- launch
extern "C" void kernel_launch(void* const* d_in, const int* in_sizes, int n_in,
                              void* d_out, int out_size, void* d_ws, size_t ws_size,
                              hipStream_t stream) {
  const float* x = (const float*)d_in[0];
  const float* Wq = (const float*)d_in[1];
  const float* Wk = (const float*)d_in[2];
  const float* Wv = (const float*)d_in[3];
  float* out = (float*)d_out;
  char* ws = (char*)d_ws;
  __bf16* Qb = (__bf16*)(ws);                             // 8 MB
  __bf16* Kb = (__bf16*)(ws + (8u << 20));                // 8 MB
  __bf16* Vb = (__bf16*)(ws + (16u << 20));               // 8 MB
  __bf16* VpT = (__bf16*)(ws + (24u << 20));              // 8 MB (blocked+swizzled)
  float* colsum = (float*)(ws + (32u << 20));             // 64 KB
  __bf16* Wb = (__bf16*)(ws + (32u << 20) + (1u << 16));  // 384 KB
  const size_t base2 = (32u << 20) + (1u << 16) + (384u << 10);
  __bf16* partial = (__bf16*)(ws + base2);                // 640 x 32 KB = 20 MB

  k_prep<<<dim3(768), dim3(256), 0, stream>>>(Wq, Wk, Wv, Wb, colsum);
  k_qkv<<<dim3(256), dim3(256), 0, stream>>>(x, Wb, Qb, Kb, Vb);
  k_scoresA<<<dim3(16 * 64), dim3(256), 0, stream>>>(Qb, Kb, colsum);
  k_vpt<<<dim3(64, 4, 4), dim3(256), 0, stream>>>(Vb, colsum, VpT, 0);
  k_fused<<<dim3(1024), dim3(256), 0, stream>>>(Qb, Kb, VpT, partial);
  k_red<<<dim3(64, 4), dim3(256), 0, stream>>>(partial, Vb, out);
}